// Round 3
// baseline (94.909 us; speedup 1.0000x reference)
//
#include <hip/hip_runtime.h>
#include <stdint.h>

#define NMOL 16
#define MS   4096
#define NA   32
#define NP   512
#define BM   64

typedef __attribute__((ext_vector_type(4))) float  f32x4;
typedef __attribute__((ext_vector_type(4))) unsigned int u32x4;
typedef __attribute__((ext_vector_type(4))) int    i32x4;
typedef __attribute__((ext_vector_type(8))) short  s16x8;
typedef unsigned int uint;
typedef unsigned short ushort;

// ws layout
#define WS_DMF_OFF   0u
#define WS_DMF_SZ    (16u*512u*512u*2u)           // 8,388,608
#define WS_META_OFF  (WS_DMF_OFF + WS_DMF_SZ)     // 8,388,608
#define WS_META_SZ   (16u*512u*4u)                // 32,768
#define WS_BASF_OFF  (WS_META_OFF + WS_META_SZ)   // 8,421,376
#define WS_BASF_SZ   (16ull*4096ull*512ull*2ull)  // 67,108,864
#define WS_SPLIT_NEED (WS_BASF_OFF + WS_BASF_SZ)  // 75,530,240

// WFN symmetry table packed px | py<<4 | pz<<8
__device__ __constant__ uint c_pw[20] = {
  0x000,
  0x001, 0x010, 0x100,
  0x002, 0x020, 0x200, 0x011, 0x101, 0x110,
  0x003, 0x030, 0x300, 0x012, 0x102, 0x120, 0x021, 0x201, 0x210, 0x111
};

__device__ __forceinline__ ushort f2bf(float f) {
  uint u = __float_as_uint(f);
  u = u + 0x7fffu + ((u >> 16) & 1u);   // RNE
  return (ushort)(u >> 16);
}
__device__ __forceinline__ float bf2f(ushort b) {
  return __uint_as_float(((uint)b) << 16);
}
__device__ __forceinline__ float powi3(float x, uint e) {
  float r = (e & 1u) ? x : 1.0f;
  float x2 = x * x;
  r *= (e & 2u) ? x2 : 1.0f;
  return r;
}
__device__ __forceinline__ void ld8f(const float* p, float* o) {
  f32x4 a = *(const f32x4*)p, b = *(const f32x4*)(p + 4);
  o[0]=a[0];o[1]=a[1];o[2]=a[2];o[3]=a[3];o[4]=b[0];o[5]=b[1];o[6]=b[2];o[7]=b[3];
}
__device__ __forceinline__ void ld8u(const uint* p, uint* o) {
  u32x4 a = *(const u32x4*)p, b = *(const u32x4*)(p + 4);
  o[0]=a[0];o[1]=a[1];o[2]=a[2];o[3]=a[3];o[4]=b[0];o[5]=b[1];o[6]=b[2];o[7]=b[3];
}
__device__ __forceinline__ void ld8i(const int* p, int* o) {
  i32x4 a = *(const i32x4*)p, b = *(const i32x4*)(p + 4);
  o[0]=a[0];o[1]=a[1];o[2]=a[2];o[3]=a[3];o[4]=b[0];o[5]=b[1];o[6]=b[2];o[7]=b[3];
}

// ---- dm fp32 [n][p][q] -> dmF bf16 fragment-packed [n][Q(32)][kblk(16)][lane(64)][8]
// dmF[..][lane][j] = dm[n][ p = kblk*32 + (lane>>4)*8 + j ][ q = Q*16 + (lane&15) ]
__global__ void dm_pack(const float* __restrict__ dm, short* __restrict__ dmF) {
  __shared__ float tile[NP * 16];   // 32 KB
  const int Q = blockIdx.x, n = blockIdx.y;
  const float* src = dm + (size_t)n * NP * NP + Q * 16;
#pragma unroll
  for (int i = 0; i < 32; ++i) {
    int e = threadIdx.x + 256 * i;
    int p = e >> 4, c = e & 15;
    tile[e] = src[(size_t)p * NP + c];
  }
  __syncthreads();
  short* dst = dmF + ((size_t)(n * 32 + Q) * 16) * 512;
#pragma unroll
  for (int i = 0; i < 4; ++i) {
    int v = threadIdx.x + 256 * i;
    int kblk = v >> 6, l = v & 63;
    int p0 = kblk * 32 + ((l >> 4) << 3);
    int col = l & 15;
    s16x8 o;
#pragma unroll
    for (int j = 0; j < 8; ++j) o[j] = (short)f2bf(tile[(p0 + j) * 16 + col]);
    *(s16x8*)(dst + (size_t)v * 8) = o;
  }
}

// ---- pack centers/sym into one u32: pw(12b) | c<<12 (5b) | invalid<<31
__global__ void meta_pack(const int* __restrict__ centers, const int* __restrict__ sym,
                          uint* __restrict__ metaP) {
  int i = blockIdx.x * 256 + threadIdx.x;     // 8192 total
  int craw = centers[i], s = sym[i];
  bool valid = (craw >= 0);
  int c  = (valid ? craw : 0) & (NA - 1);
  int si = valid ? s : 0;
  si = (si >= 0 && si < 20) ? si : 0;
  metaP[i] = c_pw[si] | ((uint)c << 12) | (valid ? 0u : 0x80000000u);
}

// ---- kernel A: basis -> basisF bf16 fragment-packed [tile(1024)][rf(4)][kblk(16)][lane(64)][8]
// element: row = rf*16 + (lane&15), p = kblk*32 + (lane>>4)*8 + j   (matches MFMA A-frag)
__global__ void basis_kernel(const float* __restrict__ dv,
                             const float* __restrict__ expg,
                             const uint* __restrict__ metaP,
                             short* __restrict__ basisF) {
  __shared__ float dv_l[BM * 99];   // 25.3 KB -> high occupancy
  const int t   = threadIdx.x;
  const int bid = blockIdx.x;
  const int n   = bid >> 6;
  const int m0  = (bid & 63) * BM;

  {
    const float* dvg = dv + (size_t)(n * MS + m0) * (NA * 3);
    for (int i4 = t; i4 < (BM * NA * 3) / 4; i4 += 256) {
      f32x4 v = ((const f32x4*)dvg)[i4];
      int flat = i4 * 4;
      int m = flat / 96;
      int r = flat - m * 96;
      float* d = dv_l + m * 99 + r;
      d[0] = v[0]; d[1] = v[1]; d[2] = v[2]; d[3] = v[3];
    }
  }
  __syncthreads();

  const int lane = t & 63, rf = t >> 6, li = lane & 15, kg = lane >> 4;
  const int row = rf * 16 + li;
  const float* drow = dv_l + row * 99;
  const float* aG = expg + n * NP;
  const uint*  mG = metaP + n * NP;
  short* outT = basisF + (size_t)bid * (4 * 16 * 512) + (size_t)rf * (16 * 512) + lane * 8;

#pragma unroll 2
  for (int kblk = 0; kblk < 16; ++kblk) {
    const int p0 = kblk * 32 + kg * 8;
    float alv[8]; uint mv[8];
    ld8f(aG + p0, alv);           // coalesced global, L1/L2-hot
    ld8u(mG + p0, mv);
    s16x8 o;
#pragma unroll
    for (int j = 0; j < 8; ++j) {
      uint mw = mv[j];
      int  c  = (int)((mw >> 12) & 31u);
      const float* dr = drow + c * 3;
      float dx = dr[0], dy = dr[1], dz = dr[2];
      float r2 = fmaf(dx, dx, fmaf(dy, dy, dz * dz));
      float e  = __expf(-alv[j] * r2);
      float v  = powi3(dx, mw & 15u) * powi3(dy, (mw >> 4) & 15u) *
                 powi3(dz, (mw >> 8) & 15u) * e;
      v = (mw & 0x80000000u) ? 0.0f : v;
      o[j] = (short)f2bf(v);
    }
    *(s16x8*)(outT + kblk * 512) = o;   // wave writes contiguous 1KB
  }
}

// ---- kernel B: GEMM + fused quadratic-form dot. LDS = 64KB basis tile (linear).
__launch_bounds__(256, 2)
__global__ void gemm_kernel(const short* __restrict__ basisF,
                            const short* __restrict__ dmF,
                            float* __restrict__ out) {
  __shared__ __align__(16) char smem[65536];
  const int t = threadIdx.x;
  // XCD swizzle (bijective, 1024 blocks): one molecule's 64 blocks share an XCD L2
  const int bid = ((blockIdx.x & 7) << 7) + (blockIdx.x >> 3);
  const int n  = bid >> 6;
  const int m0 = (bid & 63) * BM;

  // stage 64KB basis tile, linear (lane-linear ds_read_b128 later = conflict-free)
  {
    const short* tileG = basisF + (size_t)bid * (4 * 16 * 512);
#pragma unroll
    for (int it = 0; it < 16; ++it) {
      int e = it * 256 + t;
      *(s16x8*)(smem + e * 16) = *(const s16x8*)(tileG + (size_t)e * 8);
    }
  }
  __syncthreads();

  const int lane = t & 63, wv = t >> 6, li = lane & 15, kg = lane >> 4;
  const short* dmFn = dmF + (size_t)n * (32 * 16 * 512);

  float part[16];
#pragma unroll
  for (int x = 0; x < 16; ++x) part[x] = 0.0f;

#pragma unroll 1
  for (int qc = 0; qc < 2; ++qc) {
    f32x4 acc[4][4];
#pragma unroll
    for (int rf = 0; rf < 4; ++rf)
#pragma unroll
      for (int qf = 0; qf < 4; ++qf)
        acc[rf][qf] = (f32x4){0.f, 0.f, 0.f, 0.f};

    const short* bptr[4];
#pragma unroll
    for (int qf = 0; qf < 4; ++qf)
      bptr[qf] = dmFn + ((size_t)((qc * 16 + wv * 4 + qf) * 16) * 512) + lane * 8;

#pragma unroll 4
    for (int kblk = 0; kblk < 16; ++kblk) {
      s16x8 bf[4], af[4];
#pragma unroll
      for (int qf = 0; qf < 4; ++qf)
        bf[qf] = *(const s16x8*)(bptr[qf] + kblk * 512);    // 1KB coalesced, L2-hot
#pragma unroll
      for (int rf = 0; rf < 4; ++rf)
        af[rf] = *(const s16x8*)(smem + rf * 16384 + kblk * 1024 + lane * 16);
#pragma unroll
      for (int rf = 0; rf < 4; ++rf)
#pragma unroll
        for (int qf = 0; qf < 4; ++qf)
          acc[rf][qf] = __builtin_amdgcn_mfma_f32_16x16x32_bf16(
              af[rf], bf[qf], acc[rf][qf], 0, 0, 0);
    }

    // fused dot: part[m] += sum_q Y[m,q] * basis[m,q]
    // basisF elem (m,q) at byte: (m>>4)*16384 + (q>>5)*1024 + ((q>>3)&3)*256 + (m&15)*16 + (q&7)*2
#pragma unroll
    for (int rf = 0; rf < 4; ++rf) {
#pragma unroll
      for (int jj = 0; jj < 4; ++jj) {
        const uint dotbase = (uint)rf * 16384u + (uint)(kg * 4 + jj) * 16u;
        float a = part[rf * 4 + jj];
#pragma unroll
        for (int qf = 0; qf < 4; ++qf) {
          int q = qc * 256 + wv * 64 + qf * 16 + li;     // D col = lane&15
          uint addr = dotbase + (uint)(q >> 5) * 1024u + (uint)((q >> 3) & 3) * 256u
                      + (uint)((q & 7) << 1);
          float bv = bf2f(*(const ushort*)(smem + addr));
          a = fmaf(acc[rf][qf][jj], bv, a);
        }
        part[rf * 4 + jj] = a;
      }
    }
  }

  // reduce + store (atomic-free)
  __syncthreads();   // all basis reads done before rbuf overwrite
#pragma unroll
  for (int x = 0; x < 16; ++x) {
    float v = part[x];
    v += __shfl_xor(v, 1);
    v += __shfl_xor(v, 2);
    v += __shfl_xor(v, 4);
    v += __shfl_xor(v, 8);
    part[x] = v;
  }
  float* rbuf = (float*)smem;
  if (li == 0) {
#pragma unroll
    for (int rf = 0; rf < 4; ++rf)
#pragma unroll
      for (int jj = 0; jj < 4; ++jj)
        rbuf[wv * 64 + rf * 16 + kg * 4 + jj] = part[rf * 4 + jj];
  }
  __syncthreads();
  if (t < BM) {
    float s = rbuf[t] + rbuf[64 + t] + rbuf[128 + t] + rbuf[192 + t];
    out[(size_t)n * MS + m0 + t] = s;
  }
}

// ================= fallback: round-2 fused kernel (if ws too small) =================
__launch_bounds__(256, 2)
__global__ void wfn_fused(const float* __restrict__ dv,
                          const int* __restrict__ centers,
                          const float* __restrict__ expg,
                          const int* __restrict__ sym,
                          const short* __restrict__ dmF,
                          float* __restrict__ out) {
  __shared__ __align__(16) char smem[71680];
  float* dv_l     = (float*)smem;
  float* sh_alpha = (float*)(smem + 65536);
  uint*  sh_pw    = (uint*)(smem + 65536 + 2048);
  int*   sh_cid   = (int*)(smem + 65536 + 4096);

  const int t = threadIdx.x;
  const int bid = ((blockIdx.x & 7) << 7) + (blockIdx.x >> 3);
  const int n  = bid >> 6;
  const int m0 = (bid & 63) * BM;

  for (int p = t; p < NP; p += 256) {
    int craw = centers[n * NP + p];
    int s    = sym[n * NP + p];
    bool valid = (craw >= 0);
    int c  = (valid ? craw : 0) & (NA - 1);
    int si = valid ? s : 0;
    si = (si >= 0 && si < 20) ? si : 0;
    sh_alpha[p] = expg[n * NP + p];
    sh_pw[p]    = c_pw[si] | (valid ? 0u : 0x80000000u);
    sh_cid[p]   = c;
  }
  {
    const float* dvg = dv + (size_t)(n * MS + m0) * (NA * 3);
    for (int i4 = t; i4 < (BM * NA * 3) / 4; i4 += 256) {
      f32x4 v = ((const f32x4*)dvg)[i4];
      int flat = i4 * 4;
      int m = flat / 96;
      int r = flat - m * 96;
      float* d = dv_l + m * 99 + r;
      d[0] = v[0]; d[1] = v[1]; d[2] = v[2]; d[3] = v[3];
    }
  }
  __syncthreads();

  const int mloc = t & 63;
  const int pg   = t >> 6;
  s16x8 bfr[16];
#pragma unroll
  for (int i = 0; i < 16; ++i) {
    const int pbase = i * 32 + pg * 8;
    float alv[8]; uint pwv[8]; int cv[8];
    ld8f(sh_alpha + pbase, alv);
    ld8u(sh_pw + pbase, pwv);
    ld8i(sh_cid + pbase, cv);
    ushort ob[8];
#pragma unroll
    for (int j = 0; j < 8; ++j) {
      uint pw = pwv[j];
      int  c  = cv[j];
      const float* dr = dv_l + mloc * 99 + c * 3;
      float dx = dr[0], dy = dr[1], dz = dr[2];
      float r2 = fmaf(dx, dx, fmaf(dy, dy, dz * dz));
      float e  = __expf(-alv[j] * r2);
      float v  = powi3(dx, pw & 15u) * powi3(dy, (pw >> 4) & 15u) *
                 powi3(dz, (pw >> 8) & 15u) * e;
      v = (pw & 0x80000000u) ? 0.0f : v;
      ob[j] = f2bf(v);
    }
    s16x8 f;
#pragma unroll
    for (int j = 0; j < 8; ++j) f[j] = (short)ob[j];
    bfr[i] = f;
  }
  __syncthreads();
#pragma unroll
  for (int i = 0; i < 16; ++i) {
    int slot = (i * 4 + pg) ^ (mloc & 7);
    *(s16x8*)(smem + mloc * 1024 + (slot << 4)) = bfr[i];
  }
  __syncthreads();

  const int lane = t & 63;
  const int wv   = t >> 6;
  const int li   = lane & 15;
  const int kg   = lane >> 4;
  const uint aswz = (uint)(li & 7);
  const short* dmFn = dmF + (size_t)n * 32 * 16 * 512;

  float part[16];
#pragma unroll
  for (int x = 0; x < 16; ++x) part[x] = 0.0f;

#pragma unroll 1
  for (int qc = 0; qc < 2; ++qc) {
    f32x4 acc[4][4];
#pragma unroll
    for (int rf = 0; rf < 4; ++rf)
#pragma unroll
      for (int qf = 0; qf < 4; ++qf)
        acc[rf][qf] = (f32x4){0.f, 0.f, 0.f, 0.f};

    const short* bptr[4];
#pragma unroll
    for (int qf = 0; qf < 4; ++qf)
      bptr[qf] = dmFn + ((size_t)((qc * 16 + wv * 4 + qf) * 16) * 512) + lane * 8;

#pragma unroll 4
    for (int kblk = 0; kblk < 16; ++kblk) {
      s16x8 bf[4], af[4];
#pragma unroll
      for (int qf = 0; qf < 4; ++qf)
        bf[qf] = *(const s16x8*)(bptr[qf] + kblk * 512);
      const uint aoff = (((uint)(kblk * 4 + kg)) ^ aswz) << 4;
#pragma unroll
      for (int rf = 0; rf < 4; ++rf)
        af[rf] = *(const s16x8*)(smem + (rf * 16 + li) * 1024 + aoff);
#pragma unroll
      for (int rf = 0; rf < 4; ++rf)
#pragma unroll
        for (int qf = 0; qf < 4; ++qf)
          acc[rf][qf] = __builtin_amdgcn_mfma_f32_16x16x32_bf16(
              af[rf], bf[qf], acc[rf][qf], 0, 0, 0);
    }

#pragma unroll
    for (int rf = 0; rf < 4; ++rf) {
#pragma unroll
      for (int jj = 0; jj < 4; ++jj) {
        int m = rf * 16 + kg * 4 + jj;
        uint rb  = (uint)m * 1024u;
        uint msw = (uint)(m & 7);
        float a = part[rf * 4 + jj];
#pragma unroll
        for (int qf = 0; qf < 4; ++qf) {
          int qq = qc * 256 + wv * 64 + qf * 16 + li;
          uint addr = rb + ((((uint)(qq >> 3)) ^ msw) << 4) + (uint)((qq & 7) << 1);
          float bv = bf2f(*(const ushort*)(smem + addr));
          a = fmaf(acc[rf][qf][jj], bv, a);
        }
        part[rf * 4 + jj] = a;
      }
    }
  }

  __syncthreads();
#pragma unroll
  for (int x = 0; x < 16; ++x) {
    float v = part[x];
    v += __shfl_xor(v, 1);
    v += __shfl_xor(v, 2);
    v += __shfl_xor(v, 4);
    v += __shfl_xor(v, 8);
    part[x] = v;
  }
  float* rbuf = (float*)smem;
  if (li == 0) {
#pragma unroll
    for (int rf = 0; rf < 4; ++rf)
#pragma unroll
      for (int jj = 0; jj < 4; ++jj)
        rbuf[wv * 64 + rf * 16 + kg * 4 + jj] = part[rf * 4 + jj];
  }
  __syncthreads();
  if (t < BM) {
    float s = rbuf[t] + rbuf[64 + t] + rbuf[128 + t] + rbuf[192 + t];
    out[(size_t)n * MS + m0 + t] = s;
  }
}

extern "C" void kernel_launch(void* const* d_in, const int* in_sizes, int n_in,
                              void* d_out, int out_size, void* d_ws, size_t ws_size,
                              hipStream_t stream) {
  const float* dv      = (const float*)d_in[0];
  const int*   centers = (const int*)d_in[1];
  const float* expg    = (const float*)d_in[2];
  const int*   sym     = (const int*)d_in[3];
  const float* dm      = (const float*)d_in[4];
  float* out = (float*)d_out;

  char* ws = (char*)d_ws;
  short* dmF = (short*)(ws + WS_DMF_OFF);

  dm_pack<<<dim3(32, NMOL), 256, 0, stream>>>(dm, dmF);

  if (ws_size >= (size_t)WS_SPLIT_NEED) {
    uint*  metaP  = (uint*)(ws + WS_META_OFF);
    short* basisF = (short*)(ws + WS_BASF_OFF);
    meta_pack<<<dim3(32), 256, 0, stream>>>(centers, sym, metaP);
    basis_kernel<<<dim3(NMOL * (MS / BM)), 256, 0, stream>>>(dv, expg, metaP, basisF);
    gemm_kernel<<<dim3(NMOL * (MS / BM)), 256, 0, stream>>>(basisF, dmF, out);
  } else {
    wfn_fused<<<dim3(NMOL * (MS / BM)), 256, 0, stream>>>(dv, centers, expg, sym, dmF, out);
  }
}

// Round 4
// 73.114 us; speedup vs baseline: 1.2981x; 1.2981x over previous
//
#include <hip/hip_runtime.h>
#include <stdint.h>

#define NMOL 16
#define MS   4096
#define NA   32
#define NP   512
#define BM   64

typedef __attribute__((ext_vector_type(4))) float  f32x4;
typedef __attribute__((ext_vector_type(4))) unsigned int u32x4;
typedef __attribute__((ext_vector_type(8))) short  s16x8;
typedef unsigned int uint;
typedef unsigned short ushort;

// ws layout
#define WS_DMF_OFF   0u
#define WS_DMF_SZ    (16u*512u*512u*2u)           // 8,388,608
#define WS_META_OFF  (WS_DMF_OFF + WS_DMF_SZ)
#define WS_META_SZ   (16u*512u*4u)
#define WS_ALPH_OFF  (WS_META_OFF + WS_META_SZ)

// WFN symmetry table packed px | py<<4 | pz<<8
__device__ __constant__ uint c_pw[20] = {
  0x000,
  0x001, 0x010, 0x100,
  0x002, 0x020, 0x200, 0x011, 0x101, 0x110,
  0x003, 0x030, 0x300, 0x012, 0x102, 0x120, 0x021, 0x201, 0x210, 0x111
};

__device__ __forceinline__ ushort f2bf(float f) {
  uint u = __float_as_uint(f);
  u = u + 0x7fffu + ((u >> 16) & 1u);   // RNE
  return (ushort)(u >> 16);
}
__device__ __forceinline__ float bf2f(ushort b) {
  return __uint_as_float(((uint)b) << 16);
}
__device__ __forceinline__ float powi3(float x, uint e) {
  float r = (e & 1u) ? x : 1.0f;
  float x2 = x * x;
  r *= (e & 2u) ? x2 : 1.0f;
  return r;
}
__device__ __forceinline__ void ld8f(const float* p, float* o) {
  f32x4 a = *(const f32x4*)p, b = *(const f32x4*)(p + 4);
  o[0]=a[0];o[1]=a[1];o[2]=a[2];o[3]=a[3];o[4]=b[0];o[5]=b[1];o[6]=b[2];o[7]=b[3];
}
__device__ __forceinline__ void ld8u(const uint* p, uint* o) {
  u32x4 a = *(const u32x4*)p, b = *(const u32x4*)(p + 4);
  o[0]=a[0];o[1]=a[1];o[2]=a[2];o[3]=a[3];o[4]=b[0];o[5]=b[1];o[6]=b[2];o[7]=b[3];
}

// ---- dm fp32 [n][p][q] -> dmF bf16 fragment-packed [n][Q(32)][kblk(16)][lane(64)][8]
// dmF[..][lane][j] = dm[n][ p = kblk*32 + (lane>>4)*8 + j ][ q = Q*16 + (lane&15) ]
__global__ void dm_pack(const float* __restrict__ dm, short* __restrict__ dmF) {
  __shared__ float tile[NP * 16];   // 32 KB
  const int Q = blockIdx.x, n = blockIdx.y;
  const float* src = dm + (size_t)n * NP * NP + Q * 16;
#pragma unroll
  for (int i = 0; i < 32; ++i) {
    int e = threadIdx.x + 256 * i;
    int p = e >> 4, c = e & 15;
    tile[e] = src[(size_t)p * NP + c];
  }
  __syncthreads();
  short* dst = dmF + ((size_t)(n * 32 + Q) * 16) * 512;
#pragma unroll
  for (int i = 0; i < 4; ++i) {
    int v = threadIdx.x + 256 * i;
    int kblk = v >> 6, l = v & 63;
    int p0 = kblk * 32 + ((l >> 4) << 3);
    int col = l & 15;
    s16x8 o;
#pragma unroll
    for (int j = 0; j < 8; ++j) o[j] = (short)f2bf(tile[(p0 + j) * 16 + col]);
    *(s16x8*)(dst + (size_t)v * 8) = o;
  }
}

// ---- one-shot prep: meta u32 = pw(12b) | c<<12 | invalid<<31;  alphaS = alpha*log2(e)
__global__ void prep_pack(const int* __restrict__ centers, const int* __restrict__ sym,
                          const float* __restrict__ expg,
                          uint* __restrict__ metaP, float* __restrict__ alphaS) {
  int i = blockIdx.x * 256 + threadIdx.x;     // 8192 total
  int craw = centers[i], s = sym[i];
  bool valid = (craw >= 0);
  int c  = (valid ? craw : 0) & (NA - 1);
  int si = valid ? s : 0;
  si = (si >= 0 && si < 20) ? si : 0;
  metaP[i] = c_pw[si] | ((uint)c << 12) | (valid ? 0u : 0x80000000u);
  alphaS[i] = expg[i] * 1.44269504088896f;
}

// ---------------- fused basis + GEMM + quadratic-form, 8 waves / block ------------
// LDS map (68 KB -> 2 blocks/CU, 16 waves/CU):
//   [0, 65536)      phase1: dv_l f32[64][99] (25344B) | phase2: basis bf16 [64 rows][1KB] swz
//                   final: rho_buf f32[8][64]
//   [65536, 69632)  alphaS f32[512] | metaP u32[512]
__launch_bounds__(512, 4)
__global__ void wfn_fused8(const float* __restrict__ dv,
                           const float* __restrict__ alphaG,
                           const uint* __restrict__ metaG,
                           const short* __restrict__ dmF,
                           float* __restrict__ out) {
  __shared__ __align__(16) char smem[69632];
  float* dv_l     = (float*)smem;
  float* sh_alpha = (float*)(smem + 65536);
  uint*  sh_pw    = (uint*)(smem + 65536 + 2048);

  const int t = threadIdx.x;
  // XCD swizzle (bijective, 1024 blocks): one molecule's blocks share an XCD L2
  const int bid = ((blockIdx.x & 7) << 7) + (blockIdx.x >> 3);
  const int n  = bid >> 6;
  const int m0 = (bid & 63) * BM;

  // ---------------- stage meta + dv ----------------
  for (int p = t; p < NP; p += 512) {
    sh_alpha[p] = alphaG[n * NP + p];
    sh_pw[p]    = metaG[n * NP + p];
  }
  {
    const float* dvg = dv + (size_t)(n * MS + m0) * (NA * 3);
#pragma unroll
    for (int k = 0; k < 3; ++k) {
      int i4 = t + 512 * k;                  // 1536 f32x4 total
      f32x4 v = ((const f32x4*)dvg)[i4];
      int flat = i4 * 4;
      int m = flat / 96;
      int r = flat - m * 96;
      float* d = dv_l + m * 99 + r;          // stride 99: bank-spread rows
      d[0] = v[0]; d[1] = v[1]; d[2] = v[2]; d[3] = v[3];
    }
  }
  __syncthreads();

  // ---------------- basis -> registers (wave wvp owns 64 primitives) ----------------
  const int mloc = t & 63;          // row within tile (lane id)
  const int wvp  = t >> 6;          // wave 0..7
  s16x8 bfr[8];
#pragma unroll
  for (int i = 0; i < 8; ++i) {
    const int pbase = wvp * 64 + i * 8;       // wave-uniform -> LDS broadcast
    float alv[8]; uint mv[8];
    ld8f(sh_alpha + pbase, alv);
    ld8u(sh_pw + pbase, mv);
    s16x8 f;
#pragma unroll
    for (int j = 0; j < 8; ++j) {
      uint mw = mv[j];
      int  c  = (int)((mw >> 12) & 31u);
      const float* dr = dv_l + mloc * 99 + c * 3;
      float dx = dr[0], dy = dr[1], dz = dr[2];
      float r2 = fmaf(dx, dx, fmaf(dy, dy, dz * dz));
      float arg = -(alv[j] * r2);             // alpha pre-scaled by log2(e)
      float e;
      asm("v_exp_f32 %0, %1" : "=v"(e) : "v"(arg));
      float v  = powi3(dx, mw & 15u) * powi3(dy, (mw >> 4) & 15u) *
                 powi3(dz, (mw >> 8) & 15u) * e;
      v = (mw & 0x80000000u) ? 0.0f : v;
      f[j] = (short)f2bf(v);
    }
    bfr[i] = f;
  }
  __syncthreads();   // all dv_l reads done before basis overwrites region A

  // write basis tile, slot XOR-swizzled by (row&7): free 2-way on write,
  // min-cycle ds_read_b128 A-fragments on read
#pragma unroll
  for (int i = 0; i < 8; ++i) {
    int slot = (wvp * 8 + i) ^ (mloc & 7);
    *(s16x8*)(smem + mloc * 1024 + (slot << 4)) = bfr[i];
  }
  __syncthreads();   // basis visible to all waves

  // ---------------- barrier-free MFMA GEMM + fused dot ----------------
  const int lane = t & 63, wv = t >> 6, li = lane & 15, kg = lane >> 4;
  const uint aswz = (uint)(li & 7);  // (row = rf*16+li) & 7 == li & 7
  const short* dmFn = dmF + (size_t)n * (32 * 16 * 512);

  f32x4 acc[4][4];
#pragma unroll
  for (int rf = 0; rf < 4; ++rf)
#pragma unroll
    for (int qf = 0; qf < 4; ++qf)
      acc[rf][qf] = (f32x4){0.f, 0.f, 0.f, 0.f};

  const short* bptr[4];
#pragma unroll
  for (int qf = 0; qf < 4; ++qf)
    bptr[qf] = dmFn + ((size_t)((wv * 4 + qf) * 16) * 512) + lane * 8;

#pragma unroll 4
  for (int kblk = 0; kblk < 16; ++kblk) {
    s16x8 bf[4], af[4];
#pragma unroll
    for (int qf = 0; qf < 4; ++qf)
      bf[qf] = *(const s16x8*)(bptr[qf] + kblk * 512);   // 1KB coalesced, L2-hot
    const uint aoff = (((uint)(kblk * 4 + kg)) ^ aswz) << 4;
#pragma unroll
    for (int rf = 0; rf < 4; ++rf)
      af[rf] = *(const s16x8*)(smem + (rf * 16 + li) * 1024 + aoff);
#pragma unroll
    for (int rf = 0; rf < 4; ++rf)
#pragma unroll
      for (int qf = 0; qf < 4; ++qf)
        acc[rf][qf] = __builtin_amdgcn_mfma_f32_16x16x32_bf16(
            af[rf], bf[qf], acc[rf][qf], 0, 0, 0);
  }

  // fused dot: part[m] += sum_q Y[m,q] * basis[m,q]
  float part[16];
#pragma unroll
  for (int x = 0; x < 16; ++x) part[x] = 0.0f;
#pragma unroll
  for (int rf = 0; rf < 4; ++rf) {
#pragma unroll
    for (int jj = 0; jj < 4; ++jj) {
      int m = rf * 16 + kg * 4 + jj;          // D layout: row=(lane>>4)*4+reg
      uint rb  = (uint)m * 1024u;
      uint msw = (uint)(m & 7);
      float a = 0.0f;
#pragma unroll
      for (int qf = 0; qf < 4; ++qf) {
        int q = wv * 64 + qf * 16 + li;       // D col = lane&15
        uint addr = rb + ((((uint)(q >> 3)) ^ msw) << 4) + (uint)((q & 7) << 1);
        float bv = bf2f(*(const ushort*)(smem + addr));
        a = fmaf(acc[rf][qf][jj], bv, a);
      }
      part[rf * 4 + jj] = a;
    }
  }

  // ---------------- reduce + store (atomic-free, deterministic) ----------------
  __syncthreads();   // all basis reads done before rbuf overwrites row 0
#pragma unroll
  for (int x = 0; x < 16; ++x) {
    float v = part[x];
    v += __shfl_xor(v, 1);
    v += __shfl_xor(v, 2);
    v += __shfl_xor(v, 4);
    v += __shfl_xor(v, 8);
    part[x] = v;
  }
  float* rbuf = (float*)smem;
  if (li == 0) {
#pragma unroll
    for (int rf = 0; rf < 4; ++rf)
#pragma unroll
      for (int jj = 0; jj < 4; ++jj)
        rbuf[wv * 64 + rf * 16 + kg * 4 + jj] = part[rf * 4 + jj];
  }
  __syncthreads();
  if (t < BM) {
    float s = 0.0f;
#pragma unroll
    for (int w = 0; w < 8; ++w) s += rbuf[w * 64 + t];
    out[(size_t)n * MS + m0 + t] = s;
  }
}

extern "C" void kernel_launch(void* const* d_in, const int* in_sizes, int n_in,
                              void* d_out, int out_size, void* d_ws, size_t ws_size,
                              hipStream_t stream) {
  const float* dv      = (const float*)d_in[0];
  const int*   centers = (const int*)d_in[1];
  const float* expg    = (const float*)d_in[2];
  const int*   sym     = (const int*)d_in[3];
  const float* dm      = (const float*)d_in[4];
  float* out = (float*)d_out;

  char* ws = (char*)d_ws;
  short* dmF    = (short*)(ws + WS_DMF_OFF);
  uint*  metaP  = (uint*)(ws + WS_META_OFF);
  float* alphaS = (float*)(ws + WS_ALPH_OFF);

  dm_pack<<<dim3(32, NMOL), 256, 0, stream>>>(dm, dmF);
  prep_pack<<<dim3(32), 256, 0, stream>>>(centers, sym, expg, metaP, alphaS);
  wfn_fused8<<<dim3(NMOL * (MS / BM)), 512, 0, stream>>>(dv, alphaS, metaP, dmF, out);
}

// Round 5
// 65.543 us; speedup vs baseline: 1.4480x; 1.1155x over previous
//
#include <hip/hip_runtime.h>
#include <stdint.h>

#define NMOL 16
#define MS   4096
#define NA   32
#define NP   512
#define BM   64

typedef __attribute__((ext_vector_type(4))) float  f32x4;
typedef __attribute__((ext_vector_type(4))) unsigned int u32x4;
typedef __attribute__((ext_vector_type(8))) short  s16x8;
typedef unsigned int uint;
typedef unsigned short ushort;

// ws layout
#define WS_DMF_OFF   0u
#define WS_DMF_SZ    (16u*512u*512u*2u)
#define WS_M2A_OFF   (WS_DMF_OFF + WS_DMF_SZ)
#define WS_M2A_SZ    (16u*512u*4u)
#define WS_M2B_OFF   (WS_M2A_OFF + WS_M2A_SZ)
#define WS_M2B_SZ    (16u*512u*4u)
#define WS_ALPH_OFF  (WS_M2B_OFF + WS_M2B_SZ)

// WFN symmetry table packed px | py<<4 | pz<<8
__device__ __constant__ uint c_pw[20] = {
  0x000,
  0x001, 0x010, 0x100,
  0x002, 0x020, 0x200, 0x011, 0x101, 0x110,
  0x003, 0x030, 0x300, 0x012, 0x102, 0x120, 0x021, 0x201, 0x210, 0x111
};

__device__ __forceinline__ ushort f2bf(float f) {
  uint u = __float_as_uint(f);
  u = u + 0x7fffu + ((u >> 16) & 1u);   // RNE
  return (ushort)(u >> 16);
}
__device__ __forceinline__ float bf2f(ushort b) {
  return __uint_as_float(((uint)b) << 16);
}
__device__ __forceinline__ void ld8f(const float* p, float* o) {
  f32x4 a = *(const f32x4*)p, b = *(const f32x4*)(p + 4);
  o[0]=a[0];o[1]=a[1];o[2]=a[2];o[3]=a[3];o[4]=b[0];o[5]=b[1];o[6]=b[2];o[7]=b[3];
}
__device__ __forceinline__ void ld8u(const uint* p, uint* o) {
  u32x4 a = *(const u32x4*)p, b = *(const u32x4*)(p + 4);
  o[0]=a[0];o[1]=a[1];o[2]=a[2];o[3]=a[3];o[4]=b[0];o[5]=b[1];o[6]=b[2];o[7]=b[3];
}

// ---- dm fp32 [n][p][q] -> dmF bf16 fragment-packed [n][Q(32)][kblk(16)][lane(64)][8]
// dmF[..][lane][j] = dm[n][ p = kblk*32 + (lane>>4)*8 + j ][ q = Q*16 + (lane&15) ]
__global__ void dm_pack(const float* __restrict__ dm, short* __restrict__ dmF) {
  __shared__ float tile[NP * 16];   // 32 KB
  const int Q = blockIdx.x, n = blockIdx.y;
  const float* src = dm + (size_t)n * NP * NP + Q * 16;
#pragma unroll
  for (int i = 0; i < 32; ++i) {
    int e = threadIdx.x + 256 * i;
    int p = e >> 4, c = e & 15;
    tile[e] = src[(size_t)p * NP + c];
  }
  __syncthreads();
  short* dst = dmF + ((size_t)(n * 32 + Q) * 16) * 512;
#pragma unroll
  for (int i = 0; i < 4; ++i) {
    int v = threadIdx.x + 256 * i;
    int kblk = v >> 6, l = v & 63;
    int p0 = kblk * 32 + ((l >> 4) << 3);
    int col = l & 15;
    s16x8 o;
#pragma unroll
    for (int j = 0; j < 8; ++j) o[j] = (short)f2bf(tile[(p0 + j) * 16 + col]);
    *(s16x8*)(dst + (size_t)v * 8) = o;
  }
}

// ---- one-shot prep: bake LDS half-offset codes for the 3 monomial slots.
// table row (c*4+axis) lives at byte 65536 + row*128 -> half-offset 32768 + row*64.
// ones-row half-offset = 0 (basis region smem[0..128) holds f16 1.0 during phase 1).
// m2a = h0 | h1<<16 ; m2b = h2 | c<<16 ; alphaS = -alpha*log2(e)  (invalid -> exp ~ 0)
__global__ void prep_pack(const int* __restrict__ centers, const int* __restrict__ sym,
                          const float* __restrict__ expg,
                          uint* __restrict__ m2a, uint* __restrict__ m2b,
                          float* __restrict__ alphaS) {
  int i = blockIdx.x * 256 + threadIdx.x;     // 8192 total
  int craw = centers[i], s = sym[i];
  bool valid = (craw >= 0);
  uint c = (uint)((valid ? craw : 0) & (NA - 1));
  int si = valid ? s : 0;
  si = (si >= 0 && si < 20) ? si : 0;
  uint pw = c_pw[si];
  uint h[3]; int k = 0;
#pragma unroll
  for (uint ax = 0; ax < 3; ++ax) {
    uint e = (pw >> (4 * ax)) & 15u;
    for (uint r = 0; r < e; ++r) if (k < 3) h[k++] = 32768u + (c * 4u + ax) * 64u;
  }
  while (k < 3) h[k++] = 0u;                  // ones-row
  if (!valid) { h[0] = h[1] = h[2] = 0u; }
  m2a[i] = h[0] | (h[1] << 16);
  m2b[i] = h[2] | (c << 16);
  alphaS[i] = (valid ? -expg[i] : -1e5f) * 1.44269504088896f;
}

// ---------------- fused basis + GEMM + quadratic-form, 8 waves / block ------------
// LDS map (80 KB exact -> 2 blocks/CU, 16 waves/CU):
//   [0, 65536)      phase1: ones row [0,128) | phase2: basis bf16 [64 rows][1KB] swz
//                   final: rho_buf f32[8][64]
//   [65536, 81920)  comp table f16 [c(32)][x,y,z,r2][m^2c (64)]   (16 KB)
__launch_bounds__(512, 4)
__global__ void wfn_fused8(const float* __restrict__ dv,
                           const uint* __restrict__ m2aG,
                           const uint* __restrict__ m2bG,
                           const float* __restrict__ alG,
                           const short* __restrict__ dmF,
                           float* __restrict__ out) {
  __shared__ __align__(16) char smem[81920];

  const int t = threadIdx.x;
  // XCD-aware swizzle (bijective, 1024 blocks): one molecule's blocks share an XCD L2
  const int bid = ((blockIdx.x & 7) << 7) + (blockIdx.x >> 3);
  const int n  = bid >> 6;
  const int m0 = (bid & 63) * BM;

  // ---------------- phase 1a: ones row + f16 component/r2 table ----------------
  if (t < 32) *(uint*)(smem + t * 4) = 0x3C003C00u;   // 64 x f16(1.0)
  {
    const float* dvg = dv + (size_t)(n * MS + m0) * (NA * 3);
#pragma unroll
    for (int k = 0; k < 4; ++k) {
      int idx = t + 512 * k;              // 2048 (m,c) pairs
      int m = idx >> 5, c = idx & 31;
      const float* p = dvg + (m * NA + c) * 3;
      float x = p[0], y = p[1], z = p[2];
      float r2 = fmaf(x, x, fmaf(y, y, z * z));
      int ms = m ^ ((c << 1) & 63);       // XOR swizzle: free on build-write AND j-read
      char* rowb = smem + 65536 + (c * 4) * 128 + ms * 2;
      *(_Float16*)(rowb)       = (_Float16)x;
      *(_Float16*)(rowb + 128) = (_Float16)y;
      *(_Float16*)(rowb + 256) = (_Float16)z;
      *(_Float16*)(rowb + 384) = (_Float16)r2;
    }
  }
  __syncthreads();

  // ---------------- phase 1b: basis -> registers (scalarized meta) ----------------
  const int mloc = t & 63;          // row within tile (lane id)
  const int wvp  = t >> 6;          // wave 0..7, owns 64 primitives
  const uint* mA = m2aG + n * NP;
  const uint* mB = m2bG + n * NP;
  const float* aG = alG + n * NP;

  s16x8 bfr[8];
  uint a8[8], b8[8]; float al8[8];
  { int pb = wvp * 64; ld8u(mA + pb, a8); ld8u(mB + pb, b8); ld8f(aG + pb, al8); }
#pragma unroll
  for (int i = 0; i < 8; ++i) {
    uint na8[8], nb8[8]; float nal8[8];
    if (i < 7) {                      // 1-deep prefetch of next meta block
      int pb = wvp * 64 + (i + 1) * 8;
      ld8u(mA + pb, na8); ld8u(mB + pb, nb8); ld8f(aG + pb, nal8);
    }
    uint w[4];
#pragma unroll
    for (int jp = 0; jp < 4; ++jp) {
      float vp0, vp1;
#pragma unroll
      for (int jo = 0; jo < 2; ++jo) {
        int j = jp * 2 + jo;
        uint wa = __builtin_amdgcn_readfirstlane(a8[j]);
        uint wb = __builtin_amdgcn_readfirstlane(b8[j]);
        float alj = __uint_as_float(__builtin_amdgcn_readfirstlane(__float_as_uint(al8[j])));
        uint c  = wb >> 16;                                  // scalar
        uint lb = (uint)(mloc ^ (int)((c << 1) & 63u)) << 1; // per-lane
        float xv = (float)*(const _Float16*)(smem + (((wa & 0xFFFFu) << 1) + lb));
        float yv = (float)*(const _Float16*)(smem + (((wa >> 16) << 1) + lb));
        float zv = (float)*(const _Float16*)(smem + (((wb & 0xFFFFu) << 1) + lb));
        float r2 = (float)*(const _Float16*)(smem + (65536u + c * 512u + 384u + lb));
        float arg = alj * r2;
        float e;
        asm("v_exp_f32 %0, %1" : "=v"(e) : "v"(arg));
        float val = xv * yv * zv * e;
        if (jo == 0) vp0 = val; else vp1 = val;
      }
      asm("v_cvt_pk_bf16_f32 %0, %1, %2" : "=v"(w[jp]) : "v"(vp0), "v"(vp1));
    }
    s16x8 f; uint* fp = (uint*)&f;
    fp[0] = w[0]; fp[1] = w[1]; fp[2] = w[2]; fp[3] = w[3];
    bfr[i] = f;
    if (i < 7) {
#pragma unroll
      for (int j = 0; j < 8; ++j) { a8[j] = na8[j]; b8[j] = nb8[j]; al8[j] = nal8[j]; }
    }
  }
  __syncthreads();   // all table/ones reads done before basis overwrites region A

  // write basis tile, slot XOR-swizzled by (row&7): free 2-way on write,
  // min-cycle ds_read_b128 A-fragments on read
#pragma unroll
  for (int i = 0; i < 8; ++i) {
    int slot = (wvp * 8 + i) ^ (mloc & 7);
    *(s16x8*)(smem + mloc * 1024 + (slot << 4)) = bfr[i];
  }
  __syncthreads();   // basis visible to all waves

  // ---------------- barrier-free MFMA GEMM + fused dot ----------------
  const int lane = t & 63, wv = t >> 6, li = lane & 15, kg = lane >> 4;
  const uint aswz = (uint)(li & 7);  // (row = rf*16+li) & 7 == li & 7
  const short* dmFn = dmF + (size_t)n * (32 * 16 * 512);

  f32x4 acc[4][4];
#pragma unroll
  for (int rf = 0; rf < 4; ++rf)
#pragma unroll
    for (int qf = 0; qf < 4; ++qf)
      acc[rf][qf] = (f32x4){0.f, 0.f, 0.f, 0.f};

  const short* bptr[4];
#pragma unroll
  for (int qf = 0; qf < 4; ++qf)
    bptr[qf] = dmFn + ((size_t)((wv * 4 + qf) * 16) * 512) + lane * 8;

#pragma unroll 4
  for (int kblk = 0; kblk < 16; ++kblk) {
    s16x8 bf[4], af[4];
#pragma unroll
    for (int qf = 0; qf < 4; ++qf)
      bf[qf] = *(const s16x8*)(bptr[qf] + kblk * 512);   // 1KB coalesced, L2-hot
    const uint aoff = (((uint)(kblk * 4 + kg)) ^ aswz) << 4;
#pragma unroll
    for (int rf = 0; rf < 4; ++rf)
      af[rf] = *(const s16x8*)(smem + (rf * 16 + li) * 1024 + aoff);
#pragma unroll
    for (int rf = 0; rf < 4; ++rf)
#pragma unroll
      for (int qf = 0; qf < 4; ++qf)
        acc[rf][qf] = __builtin_amdgcn_mfma_f32_16x16x32_bf16(
            af[rf], bf[qf], acc[rf][qf], 0, 0, 0);
  }

  // fused dot: part[m] = sum_q Y[m,q] * basis[m,q]
  float part[16];
#pragma unroll
  for (int rf = 0; rf < 4; ++rf) {
#pragma unroll
    for (int jj = 0; jj < 4; ++jj) {
      int m = rf * 16 + kg * 4 + jj;          // D layout: row=(lane>>4)*4+reg
      uint rb  = (uint)m * 1024u;
      uint msw = (uint)(m & 7);
      float a = 0.0f;
#pragma unroll
      for (int qf = 0; qf < 4; ++qf) {
        int q = wv * 64 + qf * 16 + li;       // D col = lane&15
        uint addr = rb + ((((uint)(q >> 3)) ^ msw) << 4) + (uint)((q & 7) << 1);
        float bv = bf2f(*(const ushort*)(smem + addr));
        a = fmaf(acc[rf][qf][jj], bv, a);
      }
      part[rf * 4 + jj] = a;
    }
  }

  // ---------------- reduce + store (atomic-free, deterministic) ----------------
  __syncthreads();   // all basis reads done before rbuf overwrites row 0
#pragma unroll
  for (int x = 0; x < 16; ++x) {
    float v = part[x];
    v += __shfl_xor(v, 1);
    v += __shfl_xor(v, 2);
    v += __shfl_xor(v, 4);
    v += __shfl_xor(v, 8);
    part[x] = v;
  }
  float* rbuf = (float*)smem;
  if (li == 0) {
#pragma unroll
    for (int rf = 0; rf < 4; ++rf)
#pragma unroll
      for (int jj = 0; jj < 4; ++jj)
        rbuf[wv * 64 + rf * 16 + kg * 4 + jj] = part[rf * 4 + jj];
  }
  __syncthreads();
  if (t < BM) {
    float s = 0.0f;
#pragma unroll
    for (int w = 0; w < 8; ++w) s += rbuf[w * 64 + t];
    out[(size_t)n * MS + m0 + t] = s;
  }
}

extern "C" void kernel_launch(void* const* d_in, const int* in_sizes, int n_in,
                              void* d_out, int out_size, void* d_ws, size_t ws_size,
                              hipStream_t stream) {
  const float* dv      = (const float*)d_in[0];
  const int*   centers = (const int*)d_in[1];
  const float* expg    = (const float*)d_in[2];
  const int*   sym     = (const int*)d_in[3];
  const float* dm      = (const float*)d_in[4];
  float* out = (float*)d_out;

  char* ws = (char*)d_ws;
  short* dmF    = (short*)(ws + WS_DMF_OFF);
  uint*  m2a    = (uint*)(ws + WS_M2A_OFF);
  uint*  m2b    = (uint*)(ws + WS_M2B_OFF);
  float* alphaS = (float*)(ws + WS_ALPH_OFF);

  dm_pack<<<dim3(32, NMOL), 256, 0, stream>>>(dm, dmF);
  prep_pack<<<dim3(32), 256, 0, stream>>>(centers, sym, expg, m2a, m2b, alphaS);
  wfn_fused8<<<dim3(NMOL * (MS / BM)), 512, 0, stream>>>(dv, m2a, m2b, alphaS, dmF, out);
}